// Round 4
// baseline (406.656 us; speedup 1.0000x reference)
//
#include <hip/hip_runtime.h>
#include <hip/hip_bf16.h>
#include <math.h>

// Problem constants (fixed by the reference)
constexpr int Bc = 4;
constexpr int Nc = 2048;
constexpr int Fc = 64;    // F == F_
constexpr int Hc = 4;

typedef float f32x4 __attribute__((ext_vector_type(4)));  // native vector for nontemporal builtins

__device__ __forceinline__ float readlane_f(float v, int l) {
    return __int_as_float(__builtin_amdgcn_readlane(__float_as_int(v), l));
}

// ---------------------------------------------------------------------------
// Kernel 1: per-head projections + attention logit scalars.
//   feat_self[b,h,n,e] = sum_f X[b,n,f] * W_self[h,f,e]   (same for neigh)
//   s_self[b,h,n]      = sum_e feat_self[b,h,n,e] * a_self[h,e]
// One block per (b, h, 64-node tile). Each lane owns column e of W_self[h]
// and W_neigh[h] in REGISTERS; X row elements broadcast via v_readlane.
// ---------------------------------------------------------------------------
__global__ __launch_bounds__(256) void proj_kernel(
    const float* __restrict__ X,
    const float* __restrict__ Wself, const float* __restrict__ Wneigh,
    const float* __restrict__ aSelf, const float* __restrict__ aNeigh,
    float* __restrict__ fS, float* __restrict__ fN,
    float* __restrict__ sS, float* __restrict__ sN)
{
    const int lane = threadIdx.x & 63;
    const int wave = threadIdx.x >> 6;
    const int ntiles = Nc / 64;
    const int tile = blockIdx.x % ntiles;
    const int bh   = blockIdx.x / ntiles;
    const int h = bh % Hc;
    const int b = bh / Hc;

    float wSr[64], wNr[64];
    const float* wsb = Wself  + (size_t)h * Fc * Fc + lane;
    const float* wnb = Wneigh + (size_t)h * Fc * Fc + lane;
#pragma unroll
    for (int f = 0; f < 64; ++f) {
        wSr[f] = wsb[f * 64];
        wNr[f] = wnb[f * 64];
    }
    const float aSe = aSelf[h * Fc + lane];
    const float aNe = aNeigh[h * Fc + lane];

    for (int ni = 0; ni < 16; ++ni) {
        const int n = tile * 64 + wave * 16 + ni;
        const float x = X[((size_t)b * Nc + n) * Fc + lane];
        float accS = 0.f, accN = 0.f;
#pragma unroll
        for (int f = 0; f < 64; ++f) {
            const float xf = readlane_f(x, f);
            accS = fmaf(xf, wSr[f], accS);
            accN = fmaf(xf, wNr[f], accN);
        }
        const size_t row = (size_t)(b * Hc + h) * Nc + n;
        fS[row * Fc + lane] = accS;
        fN[row * Fc + lane] = accN;

        float rs = accS * aSe, rn = accN * aNe;
#pragma unroll
        for (int o = 32; o > 0; o >>= 1) {
            rs += __shfl_xor(rs, o, 64);
            rn += __shfl_xor(rn, o, 64);
        }
        if (lane == 0) { sS[row] = rs; sN[row] = rn; }
    }
}

// ---------------------------------------------------------------------------
// Kernel 2: ONE WAVE per (b,i) row. No LDS, no barriers, no atomics —
// 8192 fully independent waves.
//   - lane holds 8 float4s of A row (k*64+lane layout, coalesced)
//   - per head h: predicated sigmoid per held element (masked entries are
//     exactly 0 in fp32: sigmoid(-1e16)==0), shuffle-tree row sum,
//     nontemporal att row store straight from registers,
//     then sparse aggregation via wave-uniform ballot + ctz + shfl
//     (lane index switches meaning to feature e for the fN gather).
// ---------------------------------------------------------------------------
__global__ __launch_bounds__(256) void att_kernel(
    const float* __restrict__ A,
    const float* __restrict__ sS, const float* __restrict__ sN,
    const float* __restrict__ fS, const float* __restrict__ fN,
    float* __restrict__ out, float* __restrict__ att)
{
    const int lane = threadIdx.x & 63;
    const int wave = threadIdx.x >> 6;
    const int row  = blockIdx.x * 4 + wave;      // 0 .. B*N-1
    const int b = row >> 11;                     // row / Nc  (Nc == 2048)
    const int i = row & (Nc - 1);

    // A row into registers: a4[k] = row4[k*64 + lane]  (covers j = (k*64+lane)*4+c)
    const f32x4* Arow4 = (const f32x4*)(A + ((size_t)b * Nc + i) * Nc);
    f32x4 a4[8];
#pragma unroll
    for (int k = 0; k < 8; ++k)
        a4[k] = __builtin_nontemporal_load(&Arow4[k * 64 + lane]);

    for (int h = 0; h < Hc; ++h) {
        const size_t plane = (size_t)(b * Hc + h) * Nc;
        const float ssh = sS[plane + i];
        const float* sNh = sN + plane;

        // predicated sigmoids for this head
        f32x4 sig4[8];
        float lsum = 0.f;
#pragma unroll
        for (int k = 0; k < 8; ++k) {
#pragma unroll
            for (int c = 0; c < 4; ++c) {
                float sg = 0.f;
                if (a4[k][c] != 0.f) {
                    const int j = (k * 64 + lane) * 4 + c;
                    float z = ssh + sNh[j];
                    z = z > 0.f ? z : 0.2f * z;          // leaky_relu(0.2)
                    sg = 1.f / (1.f + __expf(-z));
                }
                sig4[k][c] = sg;
                lsum += sg;
            }
        }
        // wave-wide row sum
#pragma unroll
        for (int o = 32; o > 0; o >>= 1) lsum += __shfl_xor(lsum, o, 64);
        const float inv = 1.f / (1.f + lsum);

        // normalized att row, straight from registers (write-once stream)
        f32x4* dst = (f32x4*)(att + (plane + i) * (size_t)Nc);
#pragma unroll
        for (int k = 0; k < 8; ++k) {
            f32x4 vv = sig4[k] * inv;
            __builtin_nontemporal_store(vv, &dst[k * 64 + lane]);
        }

        // sparse aggregation: lane now = feature e
        float acc = fS[(plane + i) * Fc + lane];
#pragma unroll
        for (int k = 0; k < 8; ++k) {
#pragma unroll
            for (int c = 0; c < 4; ++c) {
                unsigned long long m = __ballot(sig4[k][c] != 0.f);
                while (m) {
                    const int src = __builtin_ctzll(m);
                    m &= m - 1;
                    const int j = (k * 64 + src) * 4 + c;
                    const float w = __shfl(sig4[k][c], src, 64);   // uniform src
                    acc = fmaf(w, fN[(plane + j) * Fc + lane], acc);  // 256B coalesced
                }
            }
        }
        acc *= inv;                                   // beta * fS + normalized agg
        acc = acc > 0.f ? acc : 0.f;                  // relu
        out[((size_t)b * Nc + i) * (Hc * Fc) + h * Fc + lane] = acc;
    }
}

extern "C" void kernel_launch(void* const* d_in, const int* in_sizes, int n_in,
                              void* d_out, int out_size, void* d_ws, size_t ws_size,
                              hipStream_t stream) {
    const float* X      = (const float*)d_in[0];
    const float* A      = (const float*)d_in[1];
    const float* Wself  = (const float*)d_in[2];
    const float* Wneigh = (const float*)d_in[3];
    const float* aSelf  = (const float*)d_in[4];
    const float* aNeigh = (const float*)d_in[5];

    float* out = (float*)d_out;                       // [B, N, H*F]
    float* att = out + (size_t)Bc * Nc * Hc * Fc;     // [B, H, N, N]

    float* ws = (float*)d_ws;
    float* fS = ws;                                   // [B,H,N,F]
    float* fN = fS + (size_t)Bc * Hc * Nc * Fc;       // [B,H,N,F]
    float* sS = fN + (size_t)Bc * Hc * Nc * Fc;       // [B,H,N]
    float* sN = sS + (size_t)Bc * Hc * Nc;            // [B,H,N]

    proj_kernel<<<Bc * Hc * (Nc / 64), 256, 0, stream>>>(
        X, Wself, Wneigh, aSelf, aNeigh, fS, fN, sS, sN);
    att_kernel<<<(Bc * Nc) / 4, 256, 0, stream>>>(
        A, sS, sN, fS, fN, out, att);
}

// Round 5
// 362.380 us; speedup vs baseline: 1.1222x; 1.1222x over previous
//
#include <hip/hip_runtime.h>
#include <hip/hip_bf16.h>
#include <math.h>

// Problem constants (fixed by the reference)
constexpr int Bc = 4;
constexpr int Nc = 2048;
constexpr int Fc = 64;    // F == F_
constexpr int Hc = 4;
constexpr int CAP = 128;  // fast-path nnz cap/row (seed-0 data max ~45; slow path covers rest)

typedef float f32x4 __attribute__((ext_vector_type(4)));

__device__ __forceinline__ float readlane_f(float v, int l) {
    return __int_as_float(__builtin_amdgcn_readlane(__float_as_int(v), l));
}

// ---------------------------------------------------------------------------
// Kernel 1: per-head projections + attention logit scalars.
// sN is written TRANSPOSED as sNt[b, n, h] so att can fetch all 4 heads of a
// neighbor with one f32x4 gather.
// ---------------------------------------------------------------------------
__global__ __launch_bounds__(256) void proj_kernel(
    const float* __restrict__ X,
    const float* __restrict__ Wself, const float* __restrict__ Wneigh,
    const float* __restrict__ aSelf, const float* __restrict__ aNeigh,
    float* __restrict__ fS, float* __restrict__ fN,
    float* __restrict__ sS, float* __restrict__ sNt)
{
    const int lane = threadIdx.x & 63;
    const int wave = threadIdx.x >> 6;
    const int ntiles = Nc / 64;
    const int tile = blockIdx.x % ntiles;
    const int bh   = blockIdx.x / ntiles;
    const int h = bh % Hc;
    const int b = bh / Hc;

    float wSr[64], wNr[64];
    const float* wsb = Wself  + (size_t)h * Fc * Fc + lane;
    const float* wnb = Wneigh + (size_t)h * Fc * Fc + lane;
#pragma unroll
    for (int f = 0; f < 64; ++f) {
        wSr[f] = wsb[f * 64];
        wNr[f] = wnb[f * 64];
    }
    const float aSe = aSelf[h * Fc + lane];
    const float aNe = aNeigh[h * Fc + lane];

    for (int ni = 0; ni < 16; ++ni) {
        const int n = tile * 64 + wave * 16 + ni;
        const float x = X[((size_t)b * Nc + n) * Fc + lane];
        float accS = 0.f, accN = 0.f;
#pragma unroll
        for (int f = 0; f < 64; ++f) {
            const float xf = readlane_f(x, f);
            accS = fmaf(xf, wSr[f], accS);
            accN = fmaf(xf, wNr[f], accN);
        }
        const size_t row = (size_t)(b * Hc + h) * Nc + n;
        fS[row * Fc + lane] = accS;
        fN[row * Fc + lane] = accN;

        float rs = accS * aSe, rn = accN * aNe;
#pragma unroll
        for (int o = 32; o > 0; o >>= 1) {
            rs += __shfl_xor(rs, o, 64);
            rn += __shfl_xor(rn, o, 64);
        }
        if (lane == 0) {
            sS[row] = rs;
            sNt[((size_t)b * Nc + n) * Hc + h] = rn;   // transposed
        }
    }
}

// ---------------------------------------------------------------------------
// Kernel 2: one wave per (b,i) row, list-driven, no dependent-load chains.
//  phase 0: ballot-compact nonzero j's -> LDS idx list; per-lane packed pos.
//  phase 1: lane-parallel sigmoids (one f32x4 sNt gather = all 4 heads),
//           shuffle-reduce sums, write normalized w4 list to LDS.
//  phase 2: dense att row store assembled from LDS via remembered positions.
//  phase 3: aggregation in batches of 8 j x 4 heads = 32 independent fN
//           loads in flight (vs a serial vmcnt(0) chain).
// Wave-uniform fallback (cnt > CAP) reproduces the generic algorithm.
// ---------------------------------------------------------------------------
__global__ __launch_bounds__(256) void att_kernel(
    const float* __restrict__ A,
    const float* __restrict__ sS, const float* __restrict__ sNt,
    const float* __restrict__ fS, const float* __restrict__ fN,
    float* __restrict__ out, float* __restrict__ att)
{
    __shared__ int   idx_s[4][CAP + 8];
    __shared__ f32x4 w_s[4][CAP + 8];

    const int lane = threadIdx.x & 63;
    const int wave = threadIdx.x >> 6;
    const int b = blockIdx.x & 3;                 // b = blk%4: XCD-affinity per batch
    const int i = (blockIdx.x >> 2) * 4 + wave;
    const f32x4 zero4 = {0.f, 0.f, 0.f, 0.f};

    // A row into registers (read-once stream)
    const f32x4* Arow4 = (const f32x4*)(A + ((size_t)b * Nc + i) * Nc);
    f32x4 a4[8];
#pragma unroll
    for (int k = 0; k < 8; ++k)
        a4[k] = __builtin_nontemporal_load(&Arow4[k * 64 + lane]);

    float ss4[Hc];
#pragma unroll
    for (int h = 0; h < Hc; ++h) ss4[h] = sS[((size_t)(b * Hc + h)) * Nc + i];

    const f32x4* sNt4 = (const f32x4*)(sNt + (size_t)b * Nc * Hc);

    // ---- phase 0: compaction ----
    int cnt = 0;
    unsigned posb[8] = {0, 0, 0, 0, 0, 0, 0, 0};
#pragma unroll
    for (int k = 0; k < 8; ++k) {
#pragma unroll
        for (int c = 0; c < 4; ++c) {
            const bool act = a4[k][c] != 0.f;
            const unsigned long long m = __ballot(act);
            if (m) {
                const int pre = (int)__popcll(m & ((1ull << lane) - 1ull));
                const int pos = cnt + pre;
                if (act) {
                    posb[k] |= (unsigned)(pos & 255) << (8 * c);
                    if (pos < CAP) idx_s[wave][pos] = (k * 64 + lane) * 4 + c;
                }
                cnt += (int)__popcll(m);
            }
        }
    }

    if (cnt <= CAP) {
        // ---- fast path ----
        if (lane < 8) idx_s[wave][cnt + lane] = i;   // pad with valid index

        // phase 1: lane-parallel sigmoids (<=2 rounds of 64)
        f32x4 sigr0 = zero4, sigr1 = zero4;
        float sum4[Hc] = {0.f, 0.f, 0.f, 0.f};
        if (lane < cnt) {
            const int j = idx_s[wave][lane];
            const f32x4 sn4 = sNt4[j];
#pragma unroll
            for (int h = 0; h < Hc; ++h) {
                float z = ss4[h] + sn4[h];
                z = z > 0.f ? z : 0.2f * z;                 // leaky_relu(0.2)
                const float sg = 1.f / (1.f + __expf(-z));
                sigr0[h] = sg; sum4[h] += sg;
            }
        }
        if (cnt > 64) {
            if (64 + lane < cnt) {
                const int j = idx_s[wave][64 + lane];
                const f32x4 sn4 = sNt4[j];
#pragma unroll
                for (int h = 0; h < Hc; ++h) {
                    float z = ss4[h] + sn4[h];
                    z = z > 0.f ? z : 0.2f * z;
                    const float sg = 1.f / (1.f + __expf(-z));
                    sigr1[h] = sg; sum4[h] += sg;
                }
            }
        }
#pragma unroll
        for (int o = 32; o > 0; o >>= 1)
#pragma unroll
            for (int h = 0; h < Hc; ++h) sum4[h] += __shfl_xor(sum4[h], o, 64);
        f32x4 inv4;
#pragma unroll
        for (int h = 0; h < Hc; ++h) inv4[h] = 1.f / (1.f + sum4[h]);

        if (lane < cnt) w_s[wave][lane] = sigr0 * inv4;
        if (cnt > 64 && 64 + lane < cnt) w_s[wave][64 + lane] = sigr1 * inv4;
        if (lane < 8) w_s[wave][cnt + lane] = zero4;         // pad w = 0

        // phase 2: dense att row stores (normalized, straight from LDS list)
#pragma unroll
        for (int k = 0; k < 8; ++k) {
            f32x4 wc[4];
#pragma unroll
            for (int c = 0; c < 4; ++c) {
                const int pos = (posb[k] >> (8 * c)) & 255;
                wc[c] = (a4[k][c] != 0.f) ? w_s[wave][pos] : zero4;
            }
#pragma unroll
            for (int h = 0; h < Hc; ++h) {
                f32x4 sg = {wc[0][h], wc[1][h], wc[2][h], wc[3][h]};
                f32x4* dst = (f32x4*)(att + (((size_t)(b * Hc + h)) * Nc + i) * (size_t)Nc);
                __builtin_nontemporal_store(sg, &dst[k * 64 + lane]);
            }
        }

        // phase 3: batched aggregation (8 j's x 4 heads = 32 loads in flight)
        f32x4 accv;
#pragma unroll
        for (int h = 0; h < Hc; ++h)
            accv[h] = fS[(((size_t)(b * Hc + h)) * Nc + i) * Fc + lane] * inv4[h];
        for (int base = 0; base < cnt; base += 8) {
            int jv[8];
#pragma unroll
            for (int u = 0; u < 8; ++u) jv[u] = idx_s[wave][base + u];
#pragma unroll
            for (int h = 0; h < Hc; ++h) {
                float wv[8], xv[8];
#pragma unroll
                for (int u = 0; u < 8; ++u) wv[u] = w_s[wave][base + u][h];
#pragma unroll
                for (int u = 0; u < 8; ++u)
                    xv[u] = fN[(((size_t)(b * Hc + h)) * Nc + jv[u]) * Fc + lane];
#pragma unroll
                for (int u = 0; u < 8; ++u) accv[h] = fmaf(wv[u], xv[u], accv[h]);
            }
        }
#pragma unroll
        for (int h = 0; h < Hc; ++h) {
            const float r = accv[h] > 0.f ? accv[h] : 0.f;
            out[((size_t)b * Nc + i) * (Hc * Fc) + h * Fc + lane] = r;
        }
    } else {
        // ---- slow generic path (never taken for this input; correctness net) ----
        for (int h = 0; h < Hc; ++h) {
            const size_t plane = (size_t)(b * Hc + h) * Nc;
            f32x4 sig4[8];
            float lsum = 0.f;
#pragma unroll
            for (int k = 0; k < 8; ++k) {
#pragma unroll
                for (int c = 0; c < 4; ++c) {
                    float sg = 0.f;
                    if (a4[k][c] != 0.f) {
                        const int j = (k * 64 + lane) * 4 + c;
                        float z = ss4[h] + sNt[((size_t)b * Nc + j) * Hc + h];
                        z = z > 0.f ? z : 0.2f * z;
                        sg = 1.f / (1.f + __expf(-z));
                    }
                    sig4[k][c] = sg;
                    lsum += sg;
                }
            }
#pragma unroll
            for (int o = 32; o > 0; o >>= 1) lsum += __shfl_xor(lsum, o, 64);
            const float inv = 1.f / (1.f + lsum);

            f32x4* dst = (f32x4*)(att + (plane + i) * (size_t)Nc);
#pragma unroll
            for (int k = 0; k < 8; ++k) {
                f32x4 vv = sig4[k] * inv;
                __builtin_nontemporal_store(vv, &dst[k * 64 + lane]);
            }

            float acc = fS[(plane + i) * Fc + lane];
#pragma unroll
            for (int k = 0; k < 8; ++k) {
#pragma unroll
                for (int c = 0; c < 4; ++c) {
                    unsigned long long m = __ballot(sig4[k][c] != 0.f);
                    while (m) {
                        const int src = __builtin_ctzll(m);
                        m &= m - 1;
                        const int j = (k * 64 + src) * 4 + c;
                        const float w = __shfl(sig4[k][c], src, 64);
                        acc = fmaf(w, fN[(plane + j) * Fc + lane], acc);
                    }
                }
            }
            acc *= inv;
            acc = acc > 0.f ? acc : 0.f;
            out[((size_t)b * Nc + i) * (Hc * Fc) + h * Fc + lane] = acc;
        }
    }
}

extern "C" void kernel_launch(void* const* d_in, const int* in_sizes, int n_in,
                              void* d_out, int out_size, void* d_ws, size_t ws_size,
                              hipStream_t stream) {
    const float* X      = (const float*)d_in[0];
    const float* A      = (const float*)d_in[1];
    const float* Wself  = (const float*)d_in[2];
    const float* Wneigh = (const float*)d_in[3];
    const float* aSelf  = (const float*)d_in[4];
    const float* aNeigh = (const float*)d_in[5];

    float* out = (float*)d_out;                       // [B, N, H*F]
    float* att = out + (size_t)Bc * Nc * Hc * Fc;     // [B, H, N, N]

    float* ws = (float*)d_ws;
    float* fS  = ws;                                  // [B,H,N,F]
    float* fN  = fS + (size_t)Bc * Hc * Nc * Fc;      // [B,H,N,F]
    float* sS  = fN + (size_t)Bc * Hc * Nc * Fc;      // [B,H,N]
    float* sNt = sS + (size_t)Bc * Hc * Nc;           // [B,N,H] transposed

    proj_kernel<<<Bc * Hc * (Nc / 64), 256, 0, stream>>>(
        X, Wself, Wneigh, aSelf, aNeigh, fS, fN, sS, sNt);
    att_kernel<<<(Bc * Nc) / 4, 256, 0, stream>>>(
        A, sS, sNt, fS, fN, out, att);
}

// Round 6
// 357.026 us; speedup vs baseline: 1.1390x; 1.0150x over previous
//
#include <hip/hip_runtime.h>
#include <hip/hip_bf16.h>
#include <math.h>

// Problem constants (fixed by the reference)
constexpr int Bc = 4;
constexpr int Nc = 2048;
constexpr int Fc = 64;    // F == F_
constexpr int Hc = 4;
constexpr int CAP = 128;  // fast-path nnz cap/row (seed-0 data max ~45; slow path covers rest)

typedef float f32x4 __attribute__((ext_vector_type(4)));

__device__ __forceinline__ float readlane_f(float v, int l) {
    return __int_as_float(__builtin_amdgcn_readlane(__float_as_int(v), l));
}

// ---------------------------------------------------------------------------
// Kernel 1: per-head projections + attention logit scalars.
// sN is written TRANSPOSED as sNt[b, n, h] so att can fetch all 4 heads of a
// neighbor with one f32x4 gather.
// ---------------------------------------------------------------------------
__global__ __launch_bounds__(256) void proj_kernel(
    const float* __restrict__ X,
    const float* __restrict__ Wself, const float* __restrict__ Wneigh,
    const float* __restrict__ aSelf, const float* __restrict__ aNeigh,
    float* __restrict__ fS, float* __restrict__ fN,
    float* __restrict__ sS, float* __restrict__ sNt)
{
    const int lane = threadIdx.x & 63;
    const int wave = threadIdx.x >> 6;
    const int ntiles = Nc / 64;
    const int tile = blockIdx.x % ntiles;
    const int bh   = blockIdx.x / ntiles;
    const int h = bh % Hc;
    const int b = bh / Hc;

    float wSr[64], wNr[64];
    const float* wsb = Wself  + (size_t)h * Fc * Fc + lane;
    const float* wnb = Wneigh + (size_t)h * Fc * Fc + lane;
#pragma unroll
    for (int f = 0; f < 64; ++f) {
        wSr[f] = wsb[f * 64];
        wNr[f] = wnb[f * 64];
    }
    const float aSe = aSelf[h * Fc + lane];
    const float aNe = aNeigh[h * Fc + lane];

    for (int ni = 0; ni < 16; ++ni) {
        const int n = tile * 64 + wave * 16 + ni;
        const float x = X[((size_t)b * Nc + n) * Fc + lane];
        float accS = 0.f, accN = 0.f;
#pragma unroll
        for (int f = 0; f < 64; ++f) {
            const float xf = readlane_f(x, f);
            accS = fmaf(xf, wSr[f], accS);
            accN = fmaf(xf, wNr[f], accN);
        }
        const size_t row = (size_t)(b * Hc + h) * Nc + n;
        fS[row * Fc + lane] = accS;
        fN[row * Fc + lane] = accN;

        float rs = accS * aSe, rn = accN * aNe;
#pragma unroll
        for (int o = 32; o > 0; o >>= 1) {
            rs += __shfl_xor(rs, o, 64);
            rn += __shfl_xor(rn, o, 64);
        }
        if (lane == 0) {
            sS[row] = rs;
            sNt[((size_t)b * Nc + n) * Hc + h] = rn;   // transposed
        }
    }
}

// ---------------------------------------------------------------------------
// Kernel 2: one wave per (b,i) row, list-driven.
//  phase 0: ballot-compact nonzero j's -> LDS idx list; per-lane packed pos.
//  phase 1: lane-parallel sigmoids (one f32x4 sNt gather = all 4 heads),
//           shuffle-reduce sums, write normalized w4 list to LDS.
//  phase 2: dense att row stores, H-OUTER: each wave writes 8 consecutive
//           1 KB segments per head-plane (contiguous 8 KB bursts) instead of
//           cycling planes at 1 KB granularity.
//  phase 3: aggregation in batches of 8 j x 4 heads = 32 independent fN
//           loads in flight.
// Wave-uniform fallback (cnt > CAP) reproduces the generic algorithm.
// ---------------------------------------------------------------------------
__global__ __launch_bounds__(256) void att_kernel(
    const float* __restrict__ A,
    const float* __restrict__ sS, const float* __restrict__ sNt,
    const float* __restrict__ fS, const float* __restrict__ fN,
    float* __restrict__ out, float* __restrict__ att)
{
    __shared__ int   idx_s[4][CAP + 8];
    __shared__ f32x4 w_s[4][CAP + 8];

    const int lane = threadIdx.x & 63;
    const int wave = threadIdx.x >> 6;
    const int b = blockIdx.x & 3;
    const int i = (blockIdx.x >> 2) * 4 + wave;
    const f32x4 zero4 = {0.f, 0.f, 0.f, 0.f};

    // A row into registers (read-once stream)
    const f32x4* Arow4 = (const f32x4*)(A + ((size_t)b * Nc + i) * Nc);
    f32x4 a4[8];
#pragma unroll
    for (int k = 0; k < 8; ++k)
        a4[k] = __builtin_nontemporal_load(&Arow4[k * 64 + lane]);

    float ss4[Hc];
#pragma unroll
    for (int h = 0; h < Hc; ++h) ss4[h] = sS[((size_t)(b * Hc + h)) * Nc + i];

    const f32x4* sNt4 = (const f32x4*)(sNt + (size_t)b * Nc * Hc);

    // ---- phase 0: compaction ----
    int cnt = 0;
    unsigned posb[8] = {0, 0, 0, 0, 0, 0, 0, 0};
#pragma unroll
    for (int k = 0; k < 8; ++k) {
#pragma unroll
        for (int c = 0; c < 4; ++c) {
            const bool act = a4[k][c] != 0.f;
            const unsigned long long m = __ballot(act);
            if (m) {
                const int pre = (int)__popcll(m & ((1ull << lane) - 1ull));
                const int pos = cnt + pre;
                if (act) {
                    posb[k] |= (unsigned)(pos & 255) << (8 * c);
                    if (pos < CAP) idx_s[wave][pos] = (k * 64 + lane) * 4 + c;
                }
                cnt += (int)__popcll(m);
            }
        }
    }

    if (cnt <= CAP) {
        // ---- fast path ----
        if (lane < 8) idx_s[wave][cnt + lane] = i;   // pad with valid index

        // phase 1: lane-parallel sigmoids (<=2 rounds of 64)
        f32x4 sigr0 = zero4, sigr1 = zero4;
        float sum4[Hc] = {0.f, 0.f, 0.f, 0.f};
        if (lane < cnt) {
            const int j = idx_s[wave][lane];
            const f32x4 sn4 = sNt4[j];
#pragma unroll
            for (int h = 0; h < Hc; ++h) {
                float z = ss4[h] + sn4[h];
                z = z > 0.f ? z : 0.2f * z;                 // leaky_relu(0.2)
                const float sg = 1.f / (1.f + __expf(-z));
                sigr0[h] = sg; sum4[h] += sg;
            }
        }
        if (cnt > 64) {
            if (64 + lane < cnt) {
                const int j = idx_s[wave][64 + lane];
                const f32x4 sn4 = sNt4[j];
#pragma unroll
                for (int h = 0; h < Hc; ++h) {
                    float z = ss4[h] + sn4[h];
                    z = z > 0.f ? z : 0.2f * z;
                    const float sg = 1.f / (1.f + __expf(-z));
                    sigr1[h] = sg; sum4[h] += sg;
                }
            }
        }
#pragma unroll
        for (int o = 32; o > 0; o >>= 1)
#pragma unroll
            for (int h = 0; h < Hc; ++h) sum4[h] += __shfl_xor(sum4[h], o, 64);
        f32x4 inv4;
#pragma unroll
        for (int h = 0; h < Hc; ++h) inv4[h] = 1.f / (1.f + sum4[h]);

        if (lane < cnt) w_s[wave][lane] = sigr0 * inv4;
        if (cnt > 64 && 64 + lane < cnt) w_s[wave][64 + lane] = sigr1 * inv4;
        if (lane < 8) w_s[wave][cnt + lane] = zero4;         // pad w = 0

        // phase 2: dense att row stores, h-outer for contiguous write bursts
#pragma unroll
        for (int h = 0; h < Hc; ++h) {
            f32x4* dst = (f32x4*)(att + (((size_t)(b * Hc + h)) * Nc + i) * (size_t)Nc);
#pragma unroll
            for (int k = 0; k < 8; ++k) {
                f32x4 sg;
#pragma unroll
                for (int c = 0; c < 4; ++c) {
                    const int pos = (posb[k] >> (8 * c)) & 255;
                    const float w = w_s[wave][pos][h];       // ds_read_b32
                    sg[c] = (a4[k][c] != 0.f) ? w : 0.f;
                }
                __builtin_nontemporal_store(sg, &dst[k * 64 + lane]);
            }
        }

        // phase 3: batched aggregation (8 j's x 4 heads = 32 loads in flight)
        f32x4 accv;
#pragma unroll
        for (int h = 0; h < Hc; ++h)
            accv[h] = fS[(((size_t)(b * Hc + h)) * Nc + i) * Fc + lane] * inv4[h];
        for (int base = 0; base < cnt; base += 8) {
            int jv[8]; f32x4 wv4[8];
#pragma unroll
            for (int u = 0; u < 8; ++u) jv[u] = idx_s[wave][base + u];
#pragma unroll
            for (int u = 0; u < 8; ++u) wv4[u] = w_s[wave][base + u];  // ds_read_b128
#pragma unroll
            for (int h = 0; h < Hc; ++h) {
                float xv[8];
#pragma unroll
                for (int u = 0; u < 8; ++u)
                    xv[u] = fN[(((size_t)(b * Hc + h)) * Nc + jv[u]) * Fc + lane];
#pragma unroll
                for (int u = 0; u < 8; ++u) accv[h] = fmaf(wv4[u][h], xv[u], accv[h]);
            }
        }
#pragma unroll
        for (int h = 0; h < Hc; ++h) {
            const float r = accv[h] > 0.f ? accv[h] : 0.f;
            out[((size_t)b * Nc + i) * (Hc * Fc) + h * Fc + lane] = r;
        }
    } else {
        // ---- slow generic path (never taken for this input; correctness net) ----
        for (int h = 0; h < Hc; ++h) {
            const size_t plane = (size_t)(b * Hc + h) * Nc;
            f32x4 sig4[8];
            float lsum = 0.f;
#pragma unroll
            for (int k = 0; k < 8; ++k) {
#pragma unroll
                for (int c = 0; c < 4; ++c) {
                    float sg = 0.f;
                    if (a4[k][c] != 0.f) {
                        const int j = (k * 64 + lane) * 4 + c;
                        float z = ss4[h] + sNt[((size_t)b * Nc + j) * Hc + h];
                        z = z > 0.f ? z : 0.2f * z;
                        sg = 1.f / (1.f + __expf(-z));
                    }
                    sig4[k][c] = sg;
                    lsum += sg;
                }
            }
#pragma unroll
            for (int o = 32; o > 0; o >>= 1) lsum += __shfl_xor(lsum, o, 64);
            const float inv = 1.f / (1.f + lsum);

            f32x4* dst = (f32x4*)(att + (plane + i) * (size_t)Nc);
#pragma unroll
            for (int k = 0; k < 8; ++k) {
                f32x4 vv = sig4[k] * inv;
                __builtin_nontemporal_store(vv, &dst[k * 64 + lane]);
            }

            float acc = fS[(plane + i) * Fc + lane];
#pragma unroll
            for (int k = 0; k < 8; ++k) {
#pragma unroll
                for (int c = 0; c < 4; ++c) {
                    unsigned long long m = __ballot(sig4[k][c] != 0.f);
                    while (m) {
                        const int src = __builtin_ctzll(m);
                        m &= m - 1;
                        const int j = (k * 64 + src) * 4 + c;
                        const float w = __shfl(sig4[k][c], src, 64);
                        acc = fmaf(w, fN[(plane + j) * Fc + lane], acc);
                    }
                }
            }
            acc *= inv;
            acc = acc > 0.f ? acc : 0.f;
            out[((size_t)b * Nc + i) * (Hc * Fc) + h * Fc + lane] = acc;
        }
    }
}

extern "C" void kernel_launch(void* const* d_in, const int* in_sizes, int n_in,
                              void* d_out, int out_size, void* d_ws, size_t ws_size,
                              hipStream_t stream) {
    const float* X      = (const float*)d_in[0];
    const float* A      = (const float*)d_in[1];
    const float* Wself  = (const float*)d_in[2];
    const float* Wneigh = (const float*)d_in[3];
    const float* aSelf  = (const float*)d_in[4];
    const float* aNeigh = (const float*)d_in[5];

    float* out = (float*)d_out;                       // [B, N, H*F]
    float* att = out + (size_t)Bc * Nc * Hc * Fc;     // [B, H, N, N]

    float* ws = (float*)d_ws;
    float* fS  = ws;                                  // [B,H,N,F]
    float* fN  = fS + (size_t)Bc * Hc * Nc * Fc;      // [B,H,N,F]
    float* sS  = fN + (size_t)Bc * Hc * Nc * Fc;      // [B,H,N]
    float* sNt = sS + (size_t)Bc * Hc * Nc;           // [B,N,H] transposed

    proj_kernel<<<Bc * Hc * (Nc / 64), 256, 0, stream>>>(
        X, Wself, Wneigh, aSelf, aNeigh, fS, fN, sS, sNt);
    att_kernel<<<(Bc * Nc) / 4, 256, 0, stream>>>(
        A, sS, sNt, fS, fN, out, att);
}

// Round 7
// 350.887 us; speedup vs baseline: 1.1589x; 1.0175x over previous
//
#include <hip/hip_runtime.h>
#include <hip/hip_bf16.h>
#include <math.h>

// Problem constants (fixed by the reference)
constexpr int Bc = 4;
constexpr int Nc = 2048;
constexpr int Fc = 64;    // F == F_
constexpr int Hc = 4;
constexpr int CAP = 128;  // fast-path nnz cap/row (seed-0 data max ~45; slow path covers rest)

typedef float f32x4 __attribute__((ext_vector_type(4)));

__device__ __forceinline__ float readlane_f(float v, int l) {
    return __int_as_float(__builtin_amdgcn_readlane(__float_as_int(v), l));
}

// ---------------------------------------------------------------------------
// Kernel 1: per-head projections + attention logit scalars.
// XCD-affinity: batch b is processed only by blocks landing on XCDs {2b,2b+1}
// (xcd = blk & 7 heuristic), so fN[b] (2 MB) is L2-resident on the same XCDs
// that att_kernel later gathers it from (L2 is write-back).
// ---------------------------------------------------------------------------
__global__ __launch_bounds__(256) void proj_kernel(
    const float* __restrict__ X,
    const float* __restrict__ Wself, const float* __restrict__ Wneigh,
    const float* __restrict__ aSelf, const float* __restrict__ aNeigh,
    float* __restrict__ fS, float* __restrict__ fN,
    float* __restrict__ sS, float* __restrict__ sNt)
{
    const int lane = threadIdx.x & 63;
    const int wave = threadIdx.x >> 6;
    // 512 blocks: b = (blk&7)>>1, local = (blk>>3)*2 + (blk&1) in [0,128)
    const int b     = (blockIdx.x & 7) >> 1;
    const int local = (blockIdx.x >> 3) * 2 + (blockIdx.x & 1);
    const int h    = local >> 5;          // 0..3
    const int tile = local & 31;          // 0..31

    float wSr[64], wNr[64];
    const float* wsb = Wself  + (size_t)h * Fc * Fc + lane;
    const float* wnb = Wneigh + (size_t)h * Fc * Fc + lane;
#pragma unroll
    for (int f = 0; f < 64; ++f) {
        wSr[f] = wsb[f * 64];
        wNr[f] = wnb[f * 64];
    }
    const float aSe = aSelf[h * Fc + lane];
    const float aNe = aNeigh[h * Fc + lane];

    for (int ni = 0; ni < 16; ++ni) {
        const int n = tile * 64 + wave * 16 + ni;
        const float x = X[((size_t)b * Nc + n) * Fc + lane];
        float accS = 0.f, accN = 0.f;
#pragma unroll
        for (int f = 0; f < 64; ++f) {
            const float xf = readlane_f(x, f);
            accS = fmaf(xf, wSr[f], accS);
            accN = fmaf(xf, wNr[f], accN);
        }
        const size_t row = (size_t)(b * Hc + h) * Nc + n;
        fS[row * Fc + lane] = accS;
        fN[row * Fc + lane] = accN;

        float rs = accS * aSe, rn = accN * aNe;
#pragma unroll
        for (int o = 32; o > 0; o >>= 1) {
            rs += __shfl_xor(rs, o, 64);
            rn += __shfl_xor(rn, o, 64);
        }
        if (lane == 0) {
            sS[row] = rs;
            sNt[((size_t)b * Nc + n) * Hc + h] = rn;   // transposed
        }
    }
}

// ---------------------------------------------------------------------------
// Kernel 2: one wave per (b,i) row, list-driven.
//  XCD-affinity block swizzle: batch b only on XCDs {2b,2b+1} -> fN[b] (2 MB)
//  stays L2-resident for the phase-3 gathers (att/A use nt and bypass L2).
//  phase 0: ballot-compact nonzero j's; per-lane packed byte positions,
//           byte 255 == "zero entry" (w_s[255] = 0) so a4 dies here (VGPR cut).
//  phase 1: lane-parallel sigmoids (f32x4 sNt gather = all 4 heads at once).
//  phase 2: dense att row stores; unconditional w_s[pos][h] LDS read.
//  phase 3: batched aggregation, 32 independent L2-hit fN loads in flight.
// ---------------------------------------------------------------------------
__global__ __launch_bounds__(256) void att_kernel(
    const float* __restrict__ A,
    const float* __restrict__ sS, const float* __restrict__ sNt,
    const float* __restrict__ fS, const float* __restrict__ fN,
    float* __restrict__ out, float* __restrict__ att)
{
    __shared__ int   idx_s[4][CAP + 8];
    __shared__ f32x4 w_s[4][256];

    const int lane = threadIdx.x & 63;
    const int wave = threadIdx.x >> 6;
    // 2048 blocks: b = (blk&7)>>1; local = (blk>>3)*2 + (blk&1) in [0,512)
    const int b     = (blockIdx.x & 7) >> 1;
    const int local = (blockIdx.x >> 3) * 2 + (blockIdx.x & 1);
    const int i     = local * 4 + wave;
    const f32x4 zero4 = {0.f, 0.f, 0.f, 0.f};

    // A row into registers (read-once stream)
    const f32x4* Arow4 = (const f32x4*)(A + ((size_t)b * Nc + i) * Nc);
    f32x4 a4[8];
#pragma unroll
    for (int k = 0; k < 8; ++k)
        a4[k] = __builtin_nontemporal_load(&Arow4[k * 64 + lane]);

    float ss4[Hc];
#pragma unroll
    for (int h = 0; h < Hc; ++h) ss4[h] = sS[((size_t)(b * Hc + h)) * Nc + i];

    const f32x4* sNt4 = (const f32x4*)(sNt + (size_t)b * Nc * Hc);

    // ---- phase 0: compaction (a4 not needed afterwards) ----
    int cnt = 0;
    unsigned posb[8];
    const unsigned long long lmask = (1ull << lane) - 1ull;
#pragma unroll
    for (int k = 0; k < 8; ++k) {
        posb[k] = 0u;
#pragma unroll
        for (int c = 0; c < 4; ++c) {
            const bool act = a4[k][c] != 0.f;
            const unsigned long long m = __ballot(act);
            const int pre = (int)__popcll(m & lmask);
            const int pos = cnt + pre;
            posb[k] |= (unsigned)(act ? (pos & 255) : 255) << (8 * c);
            if (act && pos < CAP) idx_s[wave][pos] = (k * 64 + lane) * 4 + c;
            cnt += (int)__popcll(m);
        }
    }

    if (cnt <= CAP) {
        // ---- fast path ----
        if (lane < 8) idx_s[wave][cnt + lane] = i;           // pad with valid index
        if (lane == 0) w_s[wave][255] = zero4;               // "zero entry" slot

        // phase 1: lane-parallel sigmoids (<=2 rounds of 64)
        f32x4 sigr0 = zero4, sigr1 = zero4;
        float sum4[Hc] = {0.f, 0.f, 0.f, 0.f};
        if (lane < cnt) {
            const int j = idx_s[wave][lane];
            const f32x4 sn4 = sNt4[j];
#pragma unroll
            for (int h = 0; h < Hc; ++h) {
                float z = ss4[h] + sn4[h];
                z = z > 0.f ? z : 0.2f * z;                 // leaky_relu(0.2)
                const float sg = 1.f / (1.f + __expf(-z));
                sigr0[h] = sg; sum4[h] += sg;
            }
        }
        if (cnt > 64) {
            if (64 + lane < cnt) {
                const int j = idx_s[wave][64 + lane];
                const f32x4 sn4 = sNt4[j];
#pragma unroll
                for (int h = 0; h < Hc; ++h) {
                    float z = ss4[h] + sn4[h];
                    z = z > 0.f ? z : 0.2f * z;
                    const float sg = 1.f / (1.f + __expf(-z));
                    sigr1[h] = sg; sum4[h] += sg;
                }
            }
        }
#pragma unroll
        for (int o = 32; o > 0; o >>= 1)
#pragma unroll
            for (int h = 0; h < Hc; ++h) sum4[h] += __shfl_xor(sum4[h], o, 64);
        f32x4 inv4;
#pragma unroll
        for (int h = 0; h < Hc; ++h) inv4[h] = 1.f / (1.f + sum4[h]);

        if (lane < cnt) w_s[wave][lane] = sigr0 * inv4;
        if (cnt > 64 && 64 + lane < cnt) w_s[wave][64 + lane] = sigr1 * inv4;
        if (lane < 8) w_s[wave][cnt + lane] = zero4;         // pad w = 0

        // phase 2: dense att row stores (h-outer, unconditional LDS reads)
#pragma unroll
        for (int h = 0; h < Hc; ++h) {
            f32x4* dst = (f32x4*)(att + (((size_t)(b * Hc + h)) * Nc + i) * (size_t)Nc);
#pragma unroll
            for (int k = 0; k < 8; ++k) {
                f32x4 sg;
#pragma unroll
                for (int c = 0; c < 4; ++c) {
                    const int pos = (posb[k] >> (8 * c)) & 255;
                    sg[c] = w_s[wave][pos][h];               // pos==255 -> 0
                }
                __builtin_nontemporal_store(sg, &dst[k * 64 + lane]);
            }
        }

        // phase 3: batched aggregation (8 j's x 4 heads = 32 loads in flight)
        f32x4 accv;
#pragma unroll
        for (int h = 0; h < Hc; ++h)
            accv[h] = fS[(((size_t)(b * Hc + h)) * Nc + i) * Fc + lane] * inv4[h];
        for (int base = 0; base < cnt; base += 8) {
            int jv[8]; f32x4 wv4[8];
#pragma unroll
            for (int u = 0; u < 8; ++u) jv[u] = idx_s[wave][base + u];
#pragma unroll
            for (int u = 0; u < 8; ++u) wv4[u] = w_s[wave][base + u];  // ds_read_b128
#pragma unroll
            for (int h = 0; h < Hc; ++h) {
                float xv[8];
#pragma unroll
                for (int u = 0; u < 8; ++u)
                    xv[u] = fN[(((size_t)(b * Hc + h)) * Nc + jv[u]) * Fc + lane];
#pragma unroll
                for (int u = 0; u < 8; ++u) accv[h] = fmaf(wv4[u][h], xv[u], accv[h]);
            }
        }
#pragma unroll
        for (int h = 0; h < Hc; ++h) {
            const float r = accv[h] > 0.f ? accv[h] : 0.f;
            out[((size_t)b * Nc + i) * (Hc * Fc) + h * Fc + lane] = r;
        }
    } else {
        // ---- slow generic path (never taken for this input; correctness net) ----
        for (int h = 0; h < Hc; ++h) {
            const size_t plane = (size_t)(b * Hc + h) * Nc;
            f32x4 sig4[8];
            float lsum = 0.f;
#pragma unroll
            for (int k = 0; k < 8; ++k) {
#pragma unroll
                for (int c = 0; c < 4; ++c) {
                    float sg = 0.f;
                    if (a4[k][c] != 0.f) {
                        const int j = (k * 64 + lane) * 4 + c;
                        float z = ss4[h] + sNt[((size_t)b * Nc + j) * Hc + h];
                        z = z > 0.f ? z : 0.2f * z;
                        sg = 1.f / (1.f + __expf(-z));
                    }
                    sig4[k][c] = sg;
                    lsum += sg;
                }
            }
#pragma unroll
            for (int o = 32; o > 0; o >>= 1) lsum += __shfl_xor(lsum, o, 64);
            const float inv = 1.f / (1.f + lsum);

            f32x4* dst = (f32x4*)(att + (plane + i) * (size_t)Nc);
#pragma unroll
            for (int k = 0; k < 8; ++k) {
                f32x4 vv = sig4[k] * inv;
                __builtin_nontemporal_store(vv, &dst[k * 64 + lane]);
            }

            float acc = fS[(plane + i) * Fc + lane];
#pragma unroll
            for (int k = 0; k < 8; ++k) {
#pragma unroll
                for (int c = 0; c < 4; ++c) {
                    unsigned long long m = __ballot(sig4[k][c] != 0.f);
                    while (m) {
                        const int src = __builtin_ctzll(m);
                        m &= m - 1;
                        const int j = (k * 64 + src) * 4 + c;
                        const float w = __shfl(sig4[k][c], src, 64);
                        acc = fmaf(w, fN[(plane + j) * Fc + lane], acc);
                    }
                }
            }
            acc *= inv;
            acc = acc > 0.f ? acc : 0.f;
            out[((size_t)b * Nc + i) * (Hc * Fc) + h * Fc + lane] = acc;
        }
    }
}

extern "C" void kernel_launch(void* const* d_in, const int* in_sizes, int n_in,
                              void* d_out, int out_size, void* d_ws, size_t ws_size,
                              hipStream_t stream) {
    const float* X      = (const float*)d_in[0];
    const float* A      = (const float*)d_in[1];
    const float* Wself  = (const float*)d_in[2];
    const float* Wneigh = (const float*)d_in[3];
    const float* aSelf  = (const float*)d_in[4];
    const float* aNeigh = (const float*)d_in[5];

    float* out = (float*)d_out;                       // [B, N, H*F]
    float* att = out + (size_t)Bc * Nc * Hc * Fc;     // [B, H, N, N]

    float* ws = (float*)d_ws;
    float* fS  = ws;                                  // [B,H,N,F]
    float* fN  = fS + (size_t)Bc * Hc * Nc * Fc;      // [B,H,N,F]
    float* sS  = fN + (size_t)Bc * Hc * Nc * Fc;      // [B,H,N]
    float* sNt = sS + (size_t)Bc * Hc * Nc;           // [B,N,H] transposed

    proj_kernel<<<Bc * Hc * (Nc / 64), 256, 0, stream>>>(
        X, Wself, Wneigh, aSelf, aNeigh, fS, fN, sS, sNt);
    att_kernel<<<(Bc * Nc) / 4, 256, 0, stream>>>(
        A, sS, sNt, fS, fN, out, att);
}